// Round 12
// baseline (27.283 us; speedup 1.0000x reference)
//
#include <hip/hip_runtime.h>

typedef __attribute__((ext_vector_type(8))) short bf16x8;
typedef __attribute__((ext_vector_type(4))) float f32x4;

constexpr int N  = 16384;
constexpr int D  = 64;
constexpr int H  = 256;
constexpr int SB = 32;           // samples per block; 512 blocks, 2 blocks/CU
constexpr int PITCH = 272;       // ushorts per k-group row: 32*8 + 16 pad
constexpr int PLANE = 32 * PITCH;
constexpr int STAGE = 8 * PITCH;

__device__ __forceinline__ ushort f2bf(float x) {
    uint u = __float_as_uint(x);
    u += 0x7fffu + ((u >> 16) & 1u);
    return (ushort)(u >> 16);
}
// packed f32x2 -> bf16x2 (RNE), elem0 -> low half
__device__ __forceinline__ uint cvtpk(float e0, float e1) {
    uint r;
    asm("v_cvt_pk_bf16_f32 %0, %1, %2" : "=v"(r) : "v"(e0), "v"(e1));
    return r;
}
union frag_u { bf16x8 v; uint u[4]; };

__device__ __forceinline__ bf16x8 pack_hi(const float4& a, const float4& b) {
    frag_u f;
    f.u[0] = cvtpk(a.x, a.y); f.u[1] = cvtpk(a.z, a.w);
    f.u[2] = cvtpk(b.x, b.y); f.u[3] = cvtpk(b.z, b.w);
    return f.v;
}
__device__ __forceinline__ bf16x8 pack_lo(const float4& a, const float4& b, bf16x8 hi) {
    frag_u h; h.v = hi;
    frag_u f;
    f.u[0] = cvtpk(a.x - __uint_as_float(h.u[0] << 16),
                   a.y - __uint_as_float(h.u[0] & 0xffff0000u));
    f.u[1] = cvtpk(a.z - __uint_as_float(h.u[1] << 16),
                   a.w - __uint_as_float(h.u[1] & 0xffff0000u));
    f.u[2] = cvtpk(b.x - __uint_as_float(h.u[2] << 16),
                   b.y - __uint_as_float(h.u[2] & 0xffff0000u));
    f.u[3] = cvtpk(b.z - __uint_as_float(h.u[3] << 16),
                   b.w - __uint_as_float(h.u[3] & 0xffff0000u));
    return f.v;
}
// bijective sample swizzle within a 32-sample plane group
__device__ __forceinline__ int swz(int g, int i) {
    return i ^ ((i >> 2) & 3) ^ ((g & 1) << 1);
}

__global__ __launch_bounds__(256, 2) void fused_mfma(
    const float* __restrict__ S,  const float* __restrict__ Sdot,
    const float* __restrict__ W1, const float* __restrict__ b1v,
    const float* __restrict__ W2, const float* __restrict__ b2v,
    const float* __restrict__ W3, float* __restrict__ out)
{
    __shared__ ushort U[4 * STAGE + 2 * PLANE];  // ~51 KB
    __shared__ float  red[2][4][32];             // 1 KB
    __shared__ float  csd[32][2];

    ushort* const sH = U;                    // staging planes (8 d-groups)
    ushort* const sL = U + STAGE;
    ushort* const dH = U + 2 * STAGE;
    ushort* const dL = U + 3 * STAGE;
    ushort* const yH = U + 4 * STAGE;        // y / p hi planes (32 k-groups)
    ushort* const pH = U + 4 * STAGE + PLANE;

    const int t   = threadIdx.x;
    const int l   = t & 63;
    const int wid = t >> 6;              // wave 0..3, owns h-tiles wid*4 .. +3
    const int lg  = l >> 4;
    const int lc  = l & 15;
    const int s0  = blockIdx.x * SB;

    int hh[4];
    #pragma unroll
    for (int tt = 0; tt < 4; ++tt) hh[tt] = (wid * 4 + tt) * 16 + lc;

    // ---------- B1 fragments: direct from f32 W1, split hi+lo --------------
    // frag(g, h) = W1[h][g*8 .. g*8+7], contiguous 32 B per lane
    bf16x8 B1h[2][4], B1l[2][4];
    #pragma unroll
    for (int kc = 0; kc < 2; ++kc) {
        const int g = kc * 4 + lg;
        #pragma unroll
        for (int tt = 0; tt < 4; ++tt) {
            const float* wp = W1 + hh[tt] * D + g * 8;
            const float4 a = *reinterpret_cast<const float4*>(wp);
            const float4 b = *reinterpret_cast<const float4*>(wp + 4);
            B1h[kc][tt] = pack_hi(a, b);
            B1l[kc][tt] = pack_lo(a, b, B1h[kc][tt]);
        }
    }
    // phase-2 kc=0 B2 prefetch, raw f32 (converted at consume)
    float4 nf0[4], nf1[4];
    #pragma unroll
    for (int tt = 0; tt < 4; ++tt) {
        const float* wp = W2 + hh[tt] * H + lg * 8;
        nf0[tt] = *reinterpret_cast<const float4*>(wp);
        nf1[tt] = *reinterpret_cast<const float4*>(wp + 4);
    }

    float bb1[4], bb2[4], w3v[4];
    #pragma unroll
    for (int tt = 0; tt < 4; ++tt) {
        bb1[tt] = b1v[hh[tt]]; bb2[tt] = b2v[hh[tt]]; w3v[tt] = W3[hh[tt]];
    }

    // ---------- stage S/Sdot split-bf16; fused circle & s.sdot -------------
    {
        const int i = t >> 3;            // sample 0..31
        const int g = t & 7;             // d-group of 8
        const float* sp = S    + (size_t)(s0 + i) * D + g * 8;
        const float* dp = Sdot + (size_t)(s0 + i) * D + g * 8;
        const float4 s_a = reinterpret_cast<const float4*>(sp)[0];
        const float4 s_b = reinterpret_cast<const float4*>(sp)[1];
        const float4 d_a = reinterpret_cast<const float4*>(dp)[0];
        const float4 d_b = reinterpret_cast<const float4*>(dp)[1];
        const bf16x8 vsh = pack_hi(s_a, s_b);
        const bf16x8 vsl = pack_lo(s_a, s_b, vsh);
        const bf16x8 vdh = pack_hi(d_a, d_b);
        const bf16x8 vdl = pack_lo(d_a, d_b, vdh);
        float c  = s_a.x*s_a.x + s_a.y*s_a.y + s_a.z*s_a.z + s_a.w*s_a.w
                 + s_b.x*s_b.x + s_b.y*s_b.y + s_b.z*s_b.z + s_b.w*s_b.w;
        float sd = s_a.x*d_a.x + s_a.y*d_a.y + s_a.z*d_a.z + s_a.w*d_a.w
                 + s_b.x*d_b.x + s_b.y*d_b.y + s_b.z*d_b.z + s_b.w*d_b.w;
        const int off = g * PITCH + swz(g, i) * 8;
        *reinterpret_cast<bf16x8*>(&sH[off]) = vsh;
        *reinterpret_cast<bf16x8*>(&sL[off]) = vsl;
        *reinterpret_cast<bf16x8*>(&dH[off]) = vdh;
        *reinterpret_cast<bf16x8*>(&dL[off]) = vdl;
        #pragma unroll
        for (int o = 1; o < 8; o <<= 1) { c += __shfl_xor(c, o); sd += __shfl_xor(sd, o); }
        if ((t & 7) == 0) { csd[i][0] = c; csd[i][1] = sd; }
    }
    __syncthreads();                                 // (1) staging visible

    // ---------- phase 1: z1 = S@W1^T, u1 = Sdot@W1^T (full split) ----------
    bf16x8 ash[2][2], asl[2][2], adh[2][2], adl[2][2];   // [kc][mt]
    #pragma unroll
    for (int kc = 0; kc < 2; ++kc) {
        const int g = kc * 4 + lg;
        #pragma unroll
        for (int mt = 0; mt < 2; ++mt) {
            const int off = g * PITCH + swz(g, mt * 16 + lc) * 8;
            ash[kc][mt] = *reinterpret_cast<const bf16x8*>(&sH[off]);
            asl[kc][mt] = *reinterpret_cast<const bf16x8*>(&sL[off]);
            adh[kc][mt] = *reinterpret_cast<const bf16x8*>(&dH[off]);
            adl[kc][mt] = *reinterpret_cast<const bf16x8*>(&dL[off]);
        }
    }
    f32x4 z1acc[2][4], u1acc[2][4];                  // [mt][tt]
    #pragma unroll
    for (int mt = 0; mt < 2; ++mt)
        #pragma unroll
        for (int tt = 0; tt < 4; ++tt) {
            z1acc[mt][tt] = (f32x4){0,0,0,0};
            u1acc[mt][tt] = (f32x4){0,0,0,0};
        }
    #pragma unroll
    for (int kc = 0; kc < 2; ++kc) {
        __builtin_amdgcn_s_setprio(1);
        #pragma unroll
        for (int tt = 0; tt < 4; ++tt) {
            #pragma unroll
            for (int mt = 0; mt < 2; ++mt) {
                z1acc[mt][tt] = __builtin_amdgcn_mfma_f32_16x16x32_bf16(ash[kc][mt], B1h[kc][tt], z1acc[mt][tt], 0,0,0);
                z1acc[mt][tt] = __builtin_amdgcn_mfma_f32_16x16x32_bf16(asl[kc][mt], B1h[kc][tt], z1acc[mt][tt], 0,0,0);
                z1acc[mt][tt] = __builtin_amdgcn_mfma_f32_16x16x32_bf16(ash[kc][mt], B1l[kc][tt], z1acc[mt][tt], 0,0,0);
                u1acc[mt][tt] = __builtin_amdgcn_mfma_f32_16x16x32_bf16(adh[kc][mt], B1h[kc][tt], u1acc[mt][tt], 0,0,0);
                u1acc[mt][tt] = __builtin_amdgcn_mfma_f32_16x16x32_bf16(adl[kc][mt], B1h[kc][tt], u1acc[mt][tt], 0,0,0);
                u1acc[mt][tt] = __builtin_amdgcn_mfma_f32_16x16x32_bf16(adh[kc][mt], B1l[kc][tt], u1acc[mt][tt], 0,0,0);
            }
        }
        __builtin_amdgcn_s_setprio(0);
    }

    // D layout: sample row = mt*16 + lg*4 + r, col h = hh[tt]
    // publish y1 = (z1+b1)^2 and p = 2*z1*u1 as single-bf16 planes
    #pragma unroll
    for (int tt = 0; tt < 4; ++tt) {
        const int grp = hh[tt] >> 3;
        const int jb  = grp * PITCH + (hh[tt] & 7);
        #pragma unroll
        for (int mt = 0; mt < 2; ++mt) {
            #pragma unroll
            for (int r = 0; r < 4; ++r) {
                const float z  = z1acc[mt][tt][r] + bb1[tt];
                const float pv = 2.f * z * u1acc[mt][tt][r];
                const int ii = swz(grp, mt * 16 + lg * 4 + r);
                yH[jb + ii * 8] = f2bf(z * z);
                pH[jb + ii * 8] = f2bf(pv);
            }
        }
    }
    __syncthreads();                                 // (2) y/p planes visible

    // ---------- merged phase 2: z2 = y1@W2h^T  AND  q = p@W2h^T ------------
    // B2 frags converted from raw-f32 prefetch each kc; next-kc loads issued
    // right after conversion so L2 latency spans the whole MFMA pack.
    f32x4 z2acc[2][4], qacc[2][4];
    #pragma unroll
    for (int mt = 0; mt < 2; ++mt)
        #pragma unroll
        for (int tt = 0; tt < 4; ++tt) {
            z2acc[mt][tt] = (f32x4){0,0,0,0};
            qacc[mt][tt]  = (f32x4){0,0,0,0};
        }
    #pragma unroll
    for (int kc = 0; kc < 8; ++kc) {
        const int g = kc * 4 + lg;
        bf16x8 bh[4];
        #pragma unroll
        for (int tt = 0; tt < 4; ++tt) bh[tt] = pack_hi(nf0[tt], nf1[tt]);
        if (kc < 7) {                                // prefetch next-kc raw f32
            const int gn = (kc + 1) * 4 + lg;
            #pragma unroll
            for (int tt = 0; tt < 4; ++tt) {
                const float* wp = W2 + hh[tt] * H + gn * 8;
                nf0[tt] = *reinterpret_cast<const float4*>(wp);
                nf1[tt] = *reinterpret_cast<const float4*>(wp + 4);
            }
        }
        bf16x8 ayh[2], aph[2];
        #pragma unroll
        for (int mt = 0; mt < 2; ++mt) {
            const int off = g * PITCH + swz(g, mt * 16 + lc) * 8;
            ayh[mt] = *reinterpret_cast<const bf16x8*>(&yH[off]);
            aph[mt] = *reinterpret_cast<const bf16x8*>(&pH[off]);
        }
        __builtin_amdgcn_s_setprio(1);
        #pragma unroll
        for (int tt = 0; tt < 4; ++tt) {
            #pragma unroll
            for (int mt = 0; mt < 2; ++mt) {
                z2acc[mt][tt] = __builtin_amdgcn_mfma_f32_16x16x32_bf16(ayh[mt], bh[tt], z2acc[mt][tt], 0,0,0);
                qacc[mt][tt]  = __builtin_amdgcn_mfma_f32_16x16x32_bf16(aph[mt], bh[tt], qacc[mt][tt], 0,0,0);
            }
        }
        __builtin_amdgcn_s_setprio(0);
    }

    // ---------- epilogue: nn = sum w3*(z2+b2)^2 ; gd = sum 2*w3*(z2+b2)*q --
    float nnp[2][4], gdp[2][4];
    #pragma unroll
    for (int mt = 0; mt < 2; ++mt)
        #pragma unroll
        for (int r = 0; r < 4; ++r) { nnp[mt][r] = 0.f; gdp[mt][r] = 0.f; }
    #pragma unroll
    for (int tt = 0; tt < 4; ++tt) {
        #pragma unroll
        for (int mt = 0; mt < 2; ++mt) {
            #pragma unroll
            for (int r = 0; r < 4; ++r) {
                const float z = z2acc[mt][tt][r] + bb2[tt];
                nnp[mt][r] += w3v[tt] * z * z;
                gdp[mt][r] += 2.f * w3v[tt] * z * qacc[mt][tt][r];
            }
        }
    }
    #pragma unroll
    for (int mt = 0; mt < 2; ++mt)
        #pragma unroll
        for (int r = 0; r < 4; ++r) {
            float a = nnp[mt][r], b = gdp[mt][r];
            #pragma unroll
            for (int o = 1; o < 16; o <<= 1) { a += __shfl_xor(a, o); b += __shfl_xor(b, o); }
            if (lc == 0) {
                red[0][wid][mt * 16 + lg * 4 + r] = a;
                red[1][wid][mt * 16 + lg * 4 + r] = b;
            }
        }
    __syncthreads();                                 // (3) red visible

    // ---------- finalize ----------
    if (t < SB) {
        const int i = t;
        float nn = 0.f, gd = 0.f;
        #pragma unroll
        for (int w = 0; w < 4; ++w) { nn += red[0][w][i]; gd += red[1][w][i]; }
        const float c  = csd[i][0];
        const float sd = csd[i][1];
        const int n = s0 + i;
        out[n]         = nn * c;                 // V
        out[N + n]     = 2.f * nn * sd + c * gd; // Vdot
        out[2 * N + n] = c;                      // circle
    }
}

extern "C" void kernel_launch(void* const* d_in, const int* in_sizes, int n_in,
                              void* d_out, int out_size, void* d_ws, size_t ws_size,
                              hipStream_t stream) {
    const float* S    = (const float*)d_in[0];
    const float* Sdot = (const float*)d_in[1];
    const float* W1   = (const float*)d_in[2];
    const float* b1   = (const float*)d_in[3];
    const float* W2   = (const float*)d_in[4];
    const float* b2   = (const float*)d_in[5];
    const float* W3   = (const float*)d_in[6];
    float* out = (float*)d_out;

    fused_mfma<<<N / SB, 256, 0, stream>>>(S, Sdot, W1, b1, W2, b2, W3, out);
}

// Round 13
// 23.068 us; speedup vs baseline: 1.1827x; 1.1827x over previous
//
#include <hip/hip_runtime.h>

typedef __attribute__((ext_vector_type(8))) short bf16x8;
typedef __attribute__((ext_vector_type(4))) float f32x4;

constexpr int N  = 16384;
constexpr int D  = 64;
constexpr int H  = 256;
constexpr int SB = 64;           // samples per block; 256 blocks = 1 block/CU
constexpr int PITCH = 528;       // ushorts per k-group row: 64*8 + 16 pad
constexpr int PLANE = 32 * PITCH;
constexpr int STAGE = 8 * PITCH;

__device__ __forceinline__ ushort f2bf(float x) {
    uint u = __float_as_uint(x);
    u += 0x7fffu + ((u >> 16) & 1u);
    return (ushort)(u >> 16);
}
__device__ __forceinline__ float bf2f(ushort h) {
    return __uint_as_float(((uint)h) << 16);
}
// bijective sample swizzle within a plane group (acts on low 4 bits)
__device__ __forceinline__ int swz(int g, int i) {
    return i ^ ((i >> 2) & 3) ^ ((g & 1) << 1);
}

// ---------------------------------------------------------------------------
// d_ws layout (ushort units):
//   B1h @ 0       (16384)   B1l @ 16384      cols c=h1, k=d     (= W1 rows)
//   B2h @ 32768   (65536)                    cols c=h2, k=h1    (= W2 rows)
// frag layout per plane: flat = ((k>>3)*256 + c)*8 + (k&7)
// ---------------------------------------------------------------------------
__global__ void prep_weights(const float* __restrict__ W1, const float* __restrict__ W2,
                             ushort* __restrict__ ws) {
    const int t = blockIdx.x * 256 + threadIdx.x;    // 0..10239
    if (t < 8192) {                                  // B2 hi plane only
        const int h1g = t >> 8;
        const int h2  = t & 255;
        const float* src = W2 + h2 * 256 + h1g * 8;
        bf16x8 hi;
        #pragma unroll
        for (int j = 0; j < 8; ++j) hi[j] = (short)f2bf(src[j]);
        *reinterpret_cast<bf16x8*>(ws + 32768 + (h1g * 256 + h2) * 8) = hi;
    } else if (t < 10240) {                          // B1 hi+lo planes
        const int u  = t - 8192;
        const int dg = u >> 8;
        const int h1 = u & 255;
        const float* src = W1 + h1 * 64 + dg * 8;
        bf16x8 hi, lo;
        #pragma unroll
        for (int j = 0; j < 8; ++j) {
            const float x = src[j];
            const ushort xh = f2bf(x);
            hi[j] = (short)xh;
            lo[j] = (short)f2bf(x - bf2f(xh));
        }
        const int d1 = (dg * 256 + h1) * 8;
        *reinterpret_cast<bf16x8*>(ws + d1)         = hi;
        *reinterpret_cast<bf16x8*>(ws + 16384 + d1) = lo;
    }
}

__global__ __launch_bounds__(256, 1) void fused_mfma(
    const float* __restrict__ S,  const float* __restrict__ Sdot,
    const float* __restrict__ b1v, const float* __restrict__ b2v,
    const float* __restrict__ W3, const ushort* __restrict__ ws,
    float* __restrict__ out)
{
    __shared__ ushort U[4 * STAGE + 2 * PLANE];  // ~101 KB
    __shared__ float  red[2][4][64];             // 2 KB
    __shared__ float  csd[64][2];

    ushort* const sH = U;                    // staging planes (8 d-groups)
    ushort* const sL = U + STAGE;
    ushort* const dH = U + 2 * STAGE;
    ushort* const dL = U + 3 * STAGE;
    ushort* const yH = U + 4 * STAGE;        // y / p hi planes (32 k-groups)
    ushort* const pH = U + 4 * STAGE + PLANE;

    const int t   = threadIdx.x;
    const int l   = t & 63;
    const int wid = t >> 6;              // wave 0..3, owns h-tiles wid*4 .. +3
    const int lg  = l >> 4;
    const int lc  = l & 15;
    const int s0  = blockIdx.x * SB;

    int hh[4];
    #pragma unroll
    for (int tt = 0; tt < 4; ++tt) hh[tt] = (wid * 4 + tt) * 16 + lc;

    // ---------- hoisted weight fragments (issued before any barrier) -------
    bf16x8 B1h[2][4], B1l[2][4];
    #pragma unroll
    for (int kc = 0; kc < 2; ++kc) {
        const int g = kc * 4 + lg;
        #pragma unroll
        for (int tt = 0; tt < 4; ++tt) {
            const int o = (g * 256 + hh[tt]) * 8;
            B1h[kc][tt] = *reinterpret_cast<const bf16x8*>(ws + o);
            B1l[kc][tt] = *reinterpret_cast<const bf16x8*>(ws + 16384 + o);
        }
    }
    bf16x8 nbh[4];                       // phase-2 kc=0 B2h prefetch
    #pragma unroll
    for (int tt = 0; tt < 4; ++tt)
        nbh[tt] = *reinterpret_cast<const bf16x8*>(ws + 32768 + (lg * 256 + hh[tt]) * 8);

    float bb1[4], bb2[4], w3v[4];
    #pragma unroll
    for (int tt = 0; tt < 4; ++tt) {
        bb1[tt] = b1v[hh[tt]]; bb2[tt] = b2v[hh[tt]]; w3v[tt] = W3[hh[tt]];
    }

    // ---------- stage S/Sdot split-bf16; fused circle & s.sdot -------------
    // 512 items (64 samples x 8 d-groups), 2 per thread
    #pragma unroll
    for (int it = 0; it < 2; ++it) {
        const int item = t + it * 256;
        const int i = item >> 3;         // sample 0..63
        const int g = item & 7;          // d-group of 8
        const float* sp = S    + (size_t)(s0 + i) * D + g * 8;
        const float* dp = Sdot + (size_t)(s0 + i) * D + g * 8;
        const float4 s_a = reinterpret_cast<const float4*>(sp)[0];
        const float4 s_b = reinterpret_cast<const float4*>(sp)[1];
        const float4 d_a = reinterpret_cast<const float4*>(dp)[0];
        const float4 d_b = reinterpret_cast<const float4*>(dp)[1];
        const float sv[8] = {s_a.x,s_a.y,s_a.z,s_a.w,s_b.x,s_b.y,s_b.z,s_b.w};
        const float dv[8] = {d_a.x,d_a.y,d_a.z,d_a.w,d_b.x,d_b.y,d_b.z,d_b.w};
        bf16x8 vsh, vsl, vdh, vdl;
        float c = 0.f, sd = 0.f;
        #pragma unroll
        for (int j = 0; j < 8; ++j) {
            c  += sv[j] * sv[j];
            sd += sv[j] * dv[j];
            const ushort hs = f2bf(sv[j]);
            vsh[j] = (short)hs; vsl[j] = (short)f2bf(sv[j] - bf2f(hs));
            const ushort hd = f2bf(dv[j]);
            vdh[j] = (short)hd; vdl[j] = (short)f2bf(dv[j] - bf2f(hd));
        }
        const int off = g * PITCH + swz(g, i) * 8;
        *reinterpret_cast<bf16x8*>(&sH[off]) = vsh;
        *reinterpret_cast<bf16x8*>(&sL[off]) = vsl;
        *reinterpret_cast<bf16x8*>(&dH[off]) = vdh;
        *reinterpret_cast<bf16x8*>(&dL[off]) = vdl;
        #pragma unroll
        for (int o = 1; o < 8; o <<= 1) { c += __shfl_xor(c, o); sd += __shfl_xor(sd, o); }
        if (g == 0) { csd[i][0] = c; csd[i][1] = sd; }
    }
    __syncthreads();                                 // (1) staging visible

    // ---------- phase 1: z1 = S@W1^T, u1 = Sdot@W1^T (full split) ----------
    f32x4 z1acc[4][4], u1acc[4][4];                  // [mt][tt]
    #pragma unroll
    for (int mt = 0; mt < 4; ++mt)
        #pragma unroll
        for (int tt = 0; tt < 4; ++tt) {
            z1acc[mt][tt] = (f32x4){0,0,0,0};
            u1acc[mt][tt] = (f32x4){0,0,0,0};
        }
    #pragma unroll
    for (int kc = 0; kc < 2; ++kc) {
        const int g = kc * 4 + lg;
        bf16x8 ash[4], asl[4], adh[4], adl[4];
        #pragma unroll
        for (int mt = 0; mt < 4; ++mt) {
            const int off = g * PITCH + swz(g, mt * 16 + lc) * 8;
            ash[mt] = *reinterpret_cast<const bf16x8*>(&sH[off]);
            asl[mt] = *reinterpret_cast<const bf16x8*>(&sL[off]);
            adh[mt] = *reinterpret_cast<const bf16x8*>(&dH[off]);
            adl[mt] = *reinterpret_cast<const bf16x8*>(&dL[off]);
        }
        __builtin_amdgcn_s_setprio(1);
        #pragma unroll
        for (int tt = 0; tt < 4; ++tt) {
            #pragma unroll
            for (int mt = 0; mt < 4; ++mt) {
                z1acc[mt][tt] = __builtin_amdgcn_mfma_f32_16x16x32_bf16(ash[mt], B1h[kc][tt], z1acc[mt][tt], 0,0,0);
                z1acc[mt][tt] = __builtin_amdgcn_mfma_f32_16x16x32_bf16(asl[mt], B1h[kc][tt], z1acc[mt][tt], 0,0,0);
                z1acc[mt][tt] = __builtin_amdgcn_mfma_f32_16x16x32_bf16(ash[mt], B1l[kc][tt], z1acc[mt][tt], 0,0,0);
                u1acc[mt][tt] = __builtin_amdgcn_mfma_f32_16x16x32_bf16(adh[mt], B1h[kc][tt], u1acc[mt][tt], 0,0,0);
                u1acc[mt][tt] = __builtin_amdgcn_mfma_f32_16x16x32_bf16(adl[mt], B1h[kc][tt], u1acc[mt][tt], 0,0,0);
                u1acc[mt][tt] = __builtin_amdgcn_mfma_f32_16x16x32_bf16(adh[mt], B1l[kc][tt], u1acc[mt][tt], 0,0,0);
            }
        }
        __builtin_amdgcn_s_setprio(0);
    }

    // D layout: sample row = mt*16 + lg*4 + r, col h = hh[tt]
    // publish y1 = (z1+b1)^2 and p = 2*z1*u1 as single-bf16 planes
    #pragma unroll
    for (int tt = 0; tt < 4; ++tt) {
        const int grp = hh[tt] >> 3;
        const int jb  = grp * PITCH + (hh[tt] & 7);
        #pragma unroll
        for (int mt = 0; mt < 4; ++mt) {
            #pragma unroll
            for (int r = 0; r < 4; ++r) {
                const float z  = z1acc[mt][tt][r] + bb1[tt];
                const float pv = 2.f * z * u1acc[mt][tt][r];
                const int ii = swz(grp, mt * 16 + lg * 4 + r);
                yH[jb + ii * 8] = f2bf(z * z);
                pH[jb + ii * 8] = f2bf(pv);
            }
        }
    }
    __syncthreads();                                 // (2) y/p planes visible

    // ---------- merged phase 2: z2 = y1@W2h^T  AND  q = p@W2h^T ------------
    f32x4 z2acc[4][4], qacc[4][4];
    #pragma unroll
    for (int mt = 0; mt < 4; ++mt)
        #pragma unroll
        for (int tt = 0; tt < 4; ++tt) {
            z2acc[mt][tt] = (f32x4){0,0,0,0};
            qacc[mt][tt]  = (f32x4){0,0,0,0};
        }
    #pragma unroll
    for (int kc = 0; kc < 8; ++kc) {
        const int g = kc * 4 + lg;
        bf16x8 bh[4];
        #pragma unroll
        for (int tt = 0; tt < 4; ++tt) bh[tt] = nbh[tt];
        if (kc < 7) {                                // prefetch next-kc B2h
            const int gn = (kc + 1) * 4 + lg;
            #pragma unroll
            for (int tt = 0; tt < 4; ++tt)
                nbh[tt] = *reinterpret_cast<const bf16x8*>(ws + 32768 + (gn * 256 + hh[tt]) * 8);
        }
        bf16x8 ayh[4], aph[4];
        #pragma unroll
        for (int mt = 0; mt < 4; ++mt) {
            const int off = g * PITCH + swz(g, mt * 16 + lc) * 8;
            ayh[mt] = *reinterpret_cast<const bf16x8*>(&yH[off]);
            aph[mt] = *reinterpret_cast<const bf16x8*>(&pH[off]);
        }
        __builtin_amdgcn_s_setprio(1);
        #pragma unroll
        for (int tt = 0; tt < 4; ++tt) {
            #pragma unroll
            for (int mt = 0; mt < 4; ++mt) {
                z2acc[mt][tt] = __builtin_amdgcn_mfma_f32_16x16x32_bf16(ayh[mt], bh[tt], z2acc[mt][tt], 0,0,0);
                qacc[mt][tt]  = __builtin_amdgcn_mfma_f32_16x16x32_bf16(aph[mt], bh[tt], qacc[mt][tt], 0,0,0);
            }
        }
        __builtin_amdgcn_s_setprio(0);
    }

    // ---------- epilogue: nn = sum w3*(z2+b2)^2 ; gd = sum 2*w3*(z2+b2)*q --
    float nnp[4][4], gdp[4][4];                      // [mt][r]
    #pragma unroll
    for (int mt = 0; mt < 4; ++mt)
        #pragma unroll
        for (int r = 0; r < 4; ++r) { nnp[mt][r] = 0.f; gdp[mt][r] = 0.f; }
    #pragma unroll
    for (int tt = 0; tt < 4; ++tt) {
        #pragma unroll
        for (int mt = 0; mt < 4; ++mt) {
            #pragma unroll
            for (int r = 0; r < 4; ++r) {
                const float z = z2acc[mt][tt][r] + bb2[tt];
                nnp[mt][r] += w3v[tt] * z * z;
                gdp[mt][r] += 2.f * w3v[tt] * z * qacc[mt][tt][r];
            }
        }
    }
    #pragma unroll
    for (int mt = 0; mt < 4; ++mt)
        #pragma unroll
        for (int r = 0; r < 4; ++r) {
            float a = nnp[mt][r], b = gdp[mt][r];
            #pragma unroll
            for (int o = 1; o < 16; o <<= 1) { a += __shfl_xor(a, o); b += __shfl_xor(b, o); }
            if (lc == 0) {
                red[0][wid][mt * 16 + lg * 4 + r] = a;
                red[1][wid][mt * 16 + lg * 4 + r] = b;
            }
        }
    __syncthreads();                                 // (3) red visible

    // ---------- finalize ----------
    if (t < SB) {
        const int i = t;
        float nn = 0.f, gd = 0.f;
        #pragma unroll
        for (int w = 0; w < 4; ++w) { nn += red[0][w][i]; gd += red[1][w][i]; }
        const float c  = csd[i][0];
        const float sd = csd[i][1];
        const int n = s0 + i;
        out[n]         = nn * c;                 // V
        out[N + n]     = 2.f * nn * sd + c * gd; // Vdot
        out[2 * N + n] = c;                      // circle
    }
}

extern "C" void kernel_launch(void* const* d_in, const int* in_sizes, int n_in,
                              void* d_out, int out_size, void* d_ws, size_t ws_size,
                              hipStream_t stream) {
    const float* S    = (const float*)d_in[0];
    const float* Sdot = (const float*)d_in[1];
    const float* W1   = (const float*)d_in[2];
    const float* b1   = (const float*)d_in[3];
    const float* W2   = (const float*)d_in[4];
    const float* b2   = (const float*)d_in[5];
    const float* W3   = (const float*)d_in[6];
    float* out = (float*)d_out;
    ushort* ws = (ushort*)d_ws;    // 192 KB weight planes

    prep_weights<<<40, 256, 0, stream>>>(W1, W2, ws);
    fused_mfma<<<N / SB, 256, 0, stream>>>(S, Sdot, b1, b2, W3, ws, out);
}

// Round 14
// 21.484 us; speedup vs baseline: 1.2699x; 1.0737x over previous
//
#include <hip/hip_runtime.h>

typedef __attribute__((ext_vector_type(8))) short bf16x8;
typedef __attribute__((ext_vector_type(4))) float f32x4;

constexpr int N  = 16384;
constexpr int D  = 64;
constexpr int H  = 256;
constexpr int SB = 32;           // samples per block; 512 blocks, 2 blocks/CU
constexpr int PITCH = 272;       // ushorts per k-group row: 32*8 + 16 pad
constexpr int PLANE = 32 * PITCH;
constexpr int STAGE = 8 * PITCH;

__device__ __forceinline__ ushort f2bf(float x) {
    uint u = __float_as_uint(x);
    u += 0x7fffu + ((u >> 16) & 1u);
    return (ushort)(u >> 16);
}
__device__ __forceinline__ float bf2f(ushort h) {
    return __uint_as_float(((uint)h) << 16);
}
// bijective sample swizzle within a 32-sample plane group
__device__ __forceinline__ int swz(int g, int i) {
    return i ^ ((i >> 2) & 3) ^ ((g & 1) << 1);
}

// ---------------------------------------------------------------------------
// d_ws layout (ushort units):
//   B1h @ 0       (16384)   B1l @ 16384      cols c=h1, k=d     (= W1 rows)
//   B2h @ 32768   (65536)                    cols c=h2, k=h1    (= W2 rows)
// frag layout per plane: flat = ((k>>3)*256 + c)*8 + (k&7)
// ---------------------------------------------------------------------------
__global__ void prep_weights(const float* __restrict__ W1, const float* __restrict__ W2,
                             ushort* __restrict__ ws) {
    const int t = blockIdx.x * 256 + threadIdx.x;    // 0..10239
    if (t < 8192) {                                  // B2 hi plane only
        const int h1g = t >> 8;
        const int h2  = t & 255;
        const float* src = W2 + h2 * 256 + h1g * 8;
        bf16x8 hi;
        #pragma unroll
        for (int j = 0; j < 8; ++j) hi[j] = (short)f2bf(src[j]);
        *reinterpret_cast<bf16x8*>(ws + 32768 + (h1g * 256 + h2) * 8) = hi;
    } else if (t < 10240) {                          // B1 hi+lo planes
        const int u  = t - 8192;
        const int dg = u >> 8;
        const int h1 = u & 255;
        const float* src = W1 + h1 * 64 + dg * 8;
        bf16x8 hi, lo;
        #pragma unroll
        for (int j = 0; j < 8; ++j) {
            const float x = src[j];
            const ushort xh = f2bf(x);
            hi[j] = (short)xh;
            lo[j] = (short)f2bf(x - bf2f(xh));
        }
        const int d1 = (dg * 256 + h1) * 8;
        *reinterpret_cast<bf16x8*>(ws + d1)         = hi;
        *reinterpret_cast<bf16x8*>(ws + 16384 + d1) = lo;
    }
}

__global__ __launch_bounds__(256, 2) void fused_mfma(
    const float* __restrict__ S,  const float* __restrict__ Sdot,
    const float* __restrict__ b1v, const float* __restrict__ b2v,
    const float* __restrict__ W3, const ushort* __restrict__ ws,
    float* __restrict__ out)
{
    __shared__ ushort U[4 * STAGE + 2 * PLANE];  // ~51 KB
    __shared__ float  red[2][4][32];             // 1 KB
    __shared__ float  csd[32][2];

    ushort* const sH = U;                    // staging planes (8 d-groups)
    ushort* const sL = U + STAGE;
    ushort* const dH = U + 2 * STAGE;
    ushort* const dL = U + 3 * STAGE;
    ushort* const yH = U + 4 * STAGE;        // y / p hi planes (32 k-groups)
    ushort* const pH = U + 4 * STAGE + PLANE;

    const int t   = threadIdx.x;
    const int l   = t & 63;
    const int wid = t >> 6;              // wave 0..3, owns h-tiles wid*4 .. +3
    const int lg  = l >> 4;
    const int lc  = l & 15;
    const int s0  = blockIdx.x * SB;

    // ---------- issue HBM loads (S/Sdot) FIRST: longest latency -----------
    const int si = t >> 3;               // sample 0..31
    const int sg = t & 7;                // d-group of 8
    const float* sp = S    + (size_t)(s0 + si) * D + sg * 8;
    const float* dp = Sdot + (size_t)(s0 + si) * D + sg * 8;
    const float4 s_a = reinterpret_cast<const float4*>(sp)[0];
    const float4 s_b = reinterpret_cast<const float4*>(sp)[1];
    const float4 d_a = reinterpret_cast<const float4*>(dp)[0];
    const float4 d_b = reinterpret_cast<const float4*>(dp)[1];

    int hh[4];
    #pragma unroll
    for (int tt = 0; tt < 4; ++tt) hh[tt] = (wid * 4 + tt) * 16 + lc;

    // ---------- weight fragments (L2-hot after first blocks) --------------
    bf16x8 B1h[2][4], B1l[2][4];
    #pragma unroll
    for (int kc = 0; kc < 2; ++kc) {
        const int g = kc * 4 + lg;
        #pragma unroll
        for (int tt = 0; tt < 4; ++tt) {
            const int o = (g * 256 + hh[tt]) * 8;
            B1h[kc][tt] = *reinterpret_cast<const bf16x8*>(ws + o);
            B1l[kc][tt] = *reinterpret_cast<const bf16x8*>(ws + 16384 + o);
        }
    }
    // phase-2 B2h prefetch, depth 2 (kc=0 and kc=1)
    bf16x8 nb0[4], nb1[4];
    #pragma unroll
    for (int tt = 0; tt < 4; ++tt) {
        nb0[tt] = *reinterpret_cast<const bf16x8*>(ws + 32768 + ((0 * 4 + lg) * 256 + hh[tt]) * 8);
        nb1[tt] = *reinterpret_cast<const bf16x8*>(ws + 32768 + ((1 * 4 + lg) * 256 + hh[tt]) * 8);
    }

    float bb1[4], bb2[4], w3v[4];
    #pragma unroll
    for (int tt = 0; tt < 4; ++tt) {
        bb1[tt] = b1v[hh[tt]]; bb2[tt] = b2v[hh[tt]]; w3v[tt] = W3[hh[tt]];
    }

    // ---------- stage S/Sdot split-bf16; fused circle & s.sdot -------------
    {
        const float sv[8] = {s_a.x,s_a.y,s_a.z,s_a.w,s_b.x,s_b.y,s_b.z,s_b.w};
        const float dv[8] = {d_a.x,d_a.y,d_a.z,d_a.w,d_b.x,d_b.y,d_b.z,d_b.w};
        bf16x8 vsh, vsl, vdh, vdl;
        float c = 0.f, sd = 0.f;
        #pragma unroll
        for (int j = 0; j < 8; ++j) {
            c  += sv[j] * sv[j];
            sd += sv[j] * dv[j];
            const ushort hs = f2bf(sv[j]);
            vsh[j] = (short)hs; vsl[j] = (short)f2bf(sv[j] - bf2f(hs));
            const ushort hd = f2bf(dv[j]);
            vdh[j] = (short)hd; vdl[j] = (short)f2bf(dv[j] - bf2f(hd));
        }
        const int off = sg * PITCH + swz(sg, si) * 8;
        *reinterpret_cast<bf16x8*>(&sH[off]) = vsh;
        *reinterpret_cast<bf16x8*>(&sL[off]) = vsl;
        *reinterpret_cast<bf16x8*>(&dH[off]) = vdh;
        *reinterpret_cast<bf16x8*>(&dL[off]) = vdl;
        #pragma unroll
        for (int o = 1; o < 8; o <<= 1) { c += __shfl_xor(c, o); sd += __shfl_xor(sd, o); }
        if (sg == 0) { csd[si][0] = c; csd[si][1] = sd; }
    }
    __syncthreads();                                 // (1) staging visible

    // ---------- phase 1: z1 = S@W1^T, u1 = Sdot@W1^T (full split) ----------
    bf16x8 ash[2][2], asl[2][2], adh[2][2], adl[2][2];   // [kc][mt]
    #pragma unroll
    for (int kc = 0; kc < 2; ++kc) {
        const int g = kc * 4 + lg;
        #pragma unroll
        for (int mt = 0; mt < 2; ++mt) {
            const int off = g * PITCH + swz(g, mt * 16 + lc) * 8;
            ash[kc][mt] = *reinterpret_cast<const bf16x8*>(&sH[off]);
            asl[kc][mt] = *reinterpret_cast<const bf16x8*>(&sL[off]);
            adh[kc][mt] = *reinterpret_cast<const bf16x8*>(&dH[off]);
            adl[kc][mt] = *reinterpret_cast<const bf16x8*>(&dL[off]);
        }
    }
    f32x4 z1acc[2][4], u1acc[2][4];                  // [mt][tt]
    #pragma unroll
    for (int mt = 0; mt < 2; ++mt)
        #pragma unroll
        for (int tt = 0; tt < 4; ++tt) {
            z1acc[mt][tt] = (f32x4){0,0,0,0};
            u1acc[mt][tt] = (f32x4){0,0,0,0};
        }
    #pragma unroll
    for (int kc = 0; kc < 2; ++kc) {
        #pragma unroll
        for (int tt = 0; tt < 4; ++tt) {
            #pragma unroll
            for (int mt = 0; mt < 2; ++mt) {
                z1acc[mt][tt] = __builtin_amdgcn_mfma_f32_16x16x32_bf16(ash[kc][mt], B1h[kc][tt], z1acc[mt][tt], 0,0,0);
                z1acc[mt][tt] = __builtin_amdgcn_mfma_f32_16x16x32_bf16(asl[kc][mt], B1h[kc][tt], z1acc[mt][tt], 0,0,0);
                z1acc[mt][tt] = __builtin_amdgcn_mfma_f32_16x16x32_bf16(ash[kc][mt], B1l[kc][tt], z1acc[mt][tt], 0,0,0);
                u1acc[mt][tt] = __builtin_amdgcn_mfma_f32_16x16x32_bf16(adh[kc][mt], B1h[kc][tt], u1acc[mt][tt], 0,0,0);
                u1acc[mt][tt] = __builtin_amdgcn_mfma_f32_16x16x32_bf16(adl[kc][mt], B1h[kc][tt], u1acc[mt][tt], 0,0,0);
                u1acc[mt][tt] = __builtin_amdgcn_mfma_f32_16x16x32_bf16(adh[kc][mt], B1l[kc][tt], u1acc[mt][tt], 0,0,0);
            }
        }
    }

    // D layout: sample row = mt*16 + lg*4 + r, col h = hh[tt]
    // publish y1 = (z1+b1)^2 and p = 2*z1*u1 as single-bf16 planes
    #pragma unroll
    for (int tt = 0; tt < 4; ++tt) {
        const int grp = hh[tt] >> 3;
        const int jb  = grp * PITCH + (hh[tt] & 7);
        #pragma unroll
        for (int mt = 0; mt < 2; ++mt) {
            #pragma unroll
            for (int r = 0; r < 4; ++r) {
                const float z  = z1acc[mt][tt][r] + bb1[tt];
                const float pv = 2.f * z * u1acc[mt][tt][r];
                const int ii = swz(grp, mt * 16 + lg * 4 + r);
                yH[jb + ii * 8] = f2bf(z * z);
                pH[jb + ii * 8] = f2bf(pv);
            }
        }
    }
    __syncthreads();                                 // (2) y/p planes visible

    // ---------- merged phase 2: z2 = y1@W2h^T  AND  q = p@W2h^T ------------
    // full unroll; B2h prefetch depth 2 covers L2 latency (~200cyc) with two
    // MFMA packs + LDS reads in between.
    f32x4 z2acc[2][4], qacc[2][4];
    #pragma unroll
    for (int mt = 0; mt < 2; ++mt)
        #pragma unroll
        for (int tt = 0; tt < 4; ++tt) {
            z2acc[mt][tt] = (f32x4){0,0,0,0};
            qacc[mt][tt]  = (f32x4){0,0,0,0};
        }
    #pragma unroll
    for (int kc = 0; kc < 8; ++kc) {
        const int g = kc * 4 + lg;
        bf16x8 bh[4];
        #pragma unroll
        for (int tt = 0; tt < 4; ++tt) { bh[tt] = nb0[tt]; nb0[tt] = nb1[tt]; }
        if (kc < 6) {                                // prefetch kc+2 B2h
            const int gn = (kc + 2) * 4 + lg;
            #pragma unroll
            for (int tt = 0; tt < 4; ++tt)
                nb1[tt] = *reinterpret_cast<const bf16x8*>(ws + 32768 + (gn * 256 + hh[tt]) * 8);
        }
        bf16x8 ayh[2], aph[2];
        #pragma unroll
        for (int mt = 0; mt < 2; ++mt) {
            const int off = g * PITCH + swz(g, mt * 16 + lc) * 8;
            ayh[mt] = *reinterpret_cast<const bf16x8*>(&yH[off]);
            aph[mt] = *reinterpret_cast<const bf16x8*>(&pH[off]);
        }
        #pragma unroll
        for (int tt = 0; tt < 4; ++tt) {
            #pragma unroll
            for (int mt = 0; mt < 2; ++mt) {
                z2acc[mt][tt] = __builtin_amdgcn_mfma_f32_16x16x32_bf16(ayh[mt], bh[tt], z2acc[mt][tt], 0,0,0);
                qacc[mt][tt]  = __builtin_amdgcn_mfma_f32_16x16x32_bf16(aph[mt], bh[tt], qacc[mt][tt], 0,0,0);
            }
        }
    }

    // ---------- epilogue: nn = sum w3*(z2+b2)^2 ; gd = sum 2*w3*(z2+b2)*q --
    float nnp[2][4], gdp[2][4];
    #pragma unroll
    for (int mt = 0; mt < 2; ++mt)
        #pragma unroll
        for (int r = 0; r < 4; ++r) { nnp[mt][r] = 0.f; gdp[mt][r] = 0.f; }
    #pragma unroll
    for (int tt = 0; tt < 4; ++tt) {
        #pragma unroll
        for (int mt = 0; mt < 2; ++mt) {
            #pragma unroll
            for (int r = 0; r < 4; ++r) {
                const float z = z2acc[mt][tt][r] + bb2[tt];
                nnp[mt][r] += w3v[tt] * z * z;
                gdp[mt][r] += 2.f * w3v[tt] * z * qacc[mt][tt][r];
            }
        }
    }
    #pragma unroll
    for (int mt = 0; mt < 2; ++mt)
        #pragma unroll
        for (int r = 0; r < 4; ++r) {
            float a = nnp[mt][r], b = gdp[mt][r];
            #pragma unroll
            for (int o = 1; o < 16; o <<= 1) { a += __shfl_xor(a, o); b += __shfl_xor(b, o); }
            if (lc == 0) {
                red[0][wid][mt * 16 + lg * 4 + r] = a;
                red[1][wid][mt * 16 + lg * 4 + r] = b;
            }
        }
    __syncthreads();                                 // (3) red visible

    // ---------- finalize ----------
    if (t < SB) {
        const int i = t;
        float nn = 0.f, gd = 0.f;
        #pragma unroll
        for (int w = 0; w < 4; ++w) { nn += red[0][w][i]; gd += red[1][w][i]; }
        const float c  = csd[i][0];
        const float sd = csd[i][1];
        const int n = s0 + i;
        out[n]         = nn * c;                 // V
        out[N + n]     = 2.f * nn * sd + c * gd; // Vdot
        out[2 * N + n] = c;                      // circle
    }
}

extern "C" void kernel_launch(void* const* d_in, const int* in_sizes, int n_in,
                              void* d_out, int out_size, void* d_ws, size_t ws_size,
                              hipStream_t stream) {
    const float* S    = (const float*)d_in[0];
    const float* Sdot = (const float*)d_in[1];
    const float* W1   = (const float*)d_in[2];
    const float* b1   = (const float*)d_in[3];
    const float* W2   = (const float*)d_in[4];
    const float* b2   = (const float*)d_in[5];
    const float* W3   = (const float*)d_in[6];
    float* out = (float*)d_out;
    ushort* ws = (ushort*)d_ws;    // 192 KB weight planes

    prep_weights<<<40, 256, 0, stream>>>(W1, W2, ws);
    fused_mfma<<<N / SB, 256, 0, stream>>>(S, Sdot, b1, b2, W3, ws, out);
}

// Round 15
// 20.321 us; speedup vs baseline: 1.3426x; 1.0573x over previous
//
#include <hip/hip_runtime.h>

typedef __attribute__((ext_vector_type(8))) short bf16x8;
typedef __attribute__((ext_vector_type(4))) float f32x4;

constexpr int N  = 16384;
constexpr int D  = 64;
constexpr int H  = 256;
constexpr int SB = 32;           // samples per block; 512 blocks, 2 blocks/CU
constexpr int PITCH = 272;       // ushorts per k-group row: 32*8 + 16 pad
constexpr int PLANE = 32 * PITCH;
constexpr int STAGE = 8 * PITCH;

__device__ __forceinline__ ushort f2bf(float x) {
    uint u = __float_as_uint(x);
    u += 0x7fffu + ((u >> 16) & 1u);
    return (ushort)(u >> 16);
}
__device__ __forceinline__ float bf2f(ushort h) {
    return __uint_as_float(((uint)h) << 16);
}
// bijective sample swizzle within a 32-sample plane group
__device__ __forceinline__ int swz(int g, int i) {
    return i ^ ((i >> 2) & 3) ^ ((g & 1) << 1);
}

// ---------------------------------------------------------------------------
// d_ws layout (ushort units):
//   B1h @ 0       (16384)   B1l @ 16384      cols c=h1, k=d     (= W1 rows)
//   B2h @ 32768   (65536)                    cols c=h2, k=h1    (= W2 rows)
// frag layout per plane: flat = ((k>>3)*256 + c)*8 + (k&7)
// ---------------------------------------------------------------------------
__global__ void prep_weights(const float* __restrict__ W1, const float* __restrict__ W2,
                             ushort* __restrict__ ws) {
    const int t = blockIdx.x * 256 + threadIdx.x;    // 0..10239
    if (t < 8192) {                                  // B2 hi plane only
        const int h1g = t >> 8;
        const int h2  = t & 255;
        const float* src = W2 + h2 * 256 + h1g * 8;
        bf16x8 hi;
        #pragma unroll
        for (int j = 0; j < 8; ++j) hi[j] = (short)f2bf(src[j]);
        *reinterpret_cast<bf16x8*>(ws + 32768 + (h1g * 256 + h2) * 8) = hi;
    } else if (t < 10240) {                          // B1 hi+lo planes
        const int u  = t - 8192;
        const int dg = u >> 8;
        const int h1 = u & 255;
        const float* src = W1 + h1 * 64 + dg * 8;
        bf16x8 hi, lo;
        #pragma unroll
        for (int j = 0; j < 8; ++j) {
            const float x = src[j];
            const ushort xh = f2bf(x);
            hi[j] = (short)xh;
            lo[j] = (short)f2bf(x - bf2f(xh));
        }
        const int d1 = (dg * 256 + h1) * 8;
        *reinterpret_cast<bf16x8*>(ws + d1)         = hi;
        *reinterpret_cast<bf16x8*>(ws + 16384 + d1) = lo;
    }
}

__global__ __launch_bounds__(256, 2) void fused_mfma(
    const float* __restrict__ S,  const float* __restrict__ Sdot,
    const float* __restrict__ b1v, const float* __restrict__ b2v,
    const float* __restrict__ W3, const ushort* __restrict__ ws,
    float* __restrict__ out)
{
    __shared__ ushort U[4 * STAGE + 2 * PLANE];  // ~51 KB
    __shared__ float  red[2][4][32];             // 1 KB
    __shared__ float  csd[32][2];

    ushort* const sH = U;                    // staging planes (8 d-groups)
    ushort* const sL = U + STAGE;
    ushort* const dH = U + 2 * STAGE;
    ushort* const dL = U + 3 * STAGE;
    ushort* const yH = U + 4 * STAGE;        // y / p hi planes (32 k-groups)
    ushort* const pH = U + 4 * STAGE + PLANE;

    const int t   = threadIdx.x;
    const int l   = t & 63;
    const int wid = t >> 6;              // wave 0..3, owns h-tiles wid*4 .. +3
    const int lg  = l >> 4;
    const int lc  = l & 15;
    const int s0  = blockIdx.x * SB;

    int hh[4];
    #pragma unroll
    for (int tt = 0; tt < 4; ++tt) hh[tt] = (wid * 4 + tt) * 16 + lc;

    // ---------- hoisted weight fragments (issued before any barrier) -------
    bf16x8 B1h[2][4], B1l[2][4];
    #pragma unroll
    for (int kc = 0; kc < 2; ++kc) {
        const int g = kc * 4 + lg;
        #pragma unroll
        for (int tt = 0; tt < 4; ++tt) {
            const int o = (g * 256 + hh[tt]) * 8;
            B1h[kc][tt] = *reinterpret_cast<const bf16x8*>(ws + o);
            B1l[kc][tt] = *reinterpret_cast<const bf16x8*>(ws + 16384 + o);
        }
    }
    bf16x8 nbh[4];                       // phase-2 kc=0 B2h prefetch
    #pragma unroll
    for (int tt = 0; tt < 4; ++tt)
        nbh[tt] = *reinterpret_cast<const bf16x8*>(ws + 32768 + (lg * 256 + hh[tt]) * 8);

    float bb1[4], bb2[4], w3v[4];
    #pragma unroll
    for (int tt = 0; tt < 4; ++tt) {
        bb1[tt] = b1v[hh[tt]]; bb2[tt] = b2v[hh[tt]]; w3v[tt] = W3[hh[tt]];
    }

    // ---------- stage S/Sdot split-bf16; fused circle & s.sdot -------------
    {
        const int i    = t >> 3;         // sample 0..31
        const int g    = t & 7;          // d-group of 8
        const float* sp = S    + (size_t)(s0 + i) * D + g * 8;
        const float* dp = Sdot + (size_t)(s0 + i) * D + g * 8;
        const float4 s_a = reinterpret_cast<const float4*>(sp)[0];
        const float4 s_b = reinterpret_cast<const float4*>(sp)[1];
        const float4 d_a = reinterpret_cast<const float4*>(dp)[0];
        const float4 d_b = reinterpret_cast<const float4*>(dp)[1];
        const float sv[8] = {s_a.x,s_a.y,s_a.z,s_a.w,s_b.x,s_b.y,s_b.z,s_b.w};
        const float dv[8] = {d_a.x,d_a.y,d_a.z,d_a.w,d_b.x,d_b.y,d_b.z,d_b.w};
        bf16x8 vsh, vsl, vdh, vdl;
        float c = 0.f, sd = 0.f;
        #pragma unroll
        for (int j = 0; j < 8; ++j) {
            c  += sv[j] * sv[j];
            sd += sv[j] * dv[j];
            const ushort hs = f2bf(sv[j]);
            vsh[j] = (short)hs; vsl[j] = (short)f2bf(sv[j] - bf2f(hs));
            const ushort hd = f2bf(dv[j]);
            vdh[j] = (short)hd; vdl[j] = (short)f2bf(dv[j] - bf2f(hd));
        }
        const int off = g * PITCH + swz(g, i) * 8;
        *reinterpret_cast<bf16x8*>(&sH[off]) = vsh;
        *reinterpret_cast<bf16x8*>(&sL[off]) = vsl;
        *reinterpret_cast<bf16x8*>(&dH[off]) = vdh;
        *reinterpret_cast<bf16x8*>(&dL[off]) = vdl;
        #pragma unroll
        for (int o = 1; o < 8; o <<= 1) { c += __shfl_xor(c, o); sd += __shfl_xor(sd, o); }
        if ((t & 7) == 0) { csd[i][0] = c; csd[i][1] = sd; }
    }
    __syncthreads();                                 // (1) staging visible

    // ---------- phase 1: z1 = S@W1^T, u1 = Sdot@W1^T (full split) ----------
    // issue ALL A-frag ds_reads upfront so latency overlaps the first pack
    bf16x8 ash[2][2], asl[2][2], adh[2][2], adl[2][2];   // [kc][mt]
    #pragma unroll
    for (int kc = 0; kc < 2; ++kc) {
        const int g = kc * 4 + lg;
        #pragma unroll
        for (int mt = 0; mt < 2; ++mt) {
            const int off = g * PITCH + swz(g, mt * 16 + lc) * 8;
            ash[kc][mt] = *reinterpret_cast<const bf16x8*>(&sH[off]);
            asl[kc][mt] = *reinterpret_cast<const bf16x8*>(&sL[off]);
            adh[kc][mt] = *reinterpret_cast<const bf16x8*>(&dH[off]);
            adl[kc][mt] = *reinterpret_cast<const bf16x8*>(&dL[off]);
        }
    }
    f32x4 z1acc[2][4], u1acc[2][4];                  // [mt][tt]
    #pragma unroll
    for (int mt = 0; mt < 2; ++mt)
        #pragma unroll
        for (int tt = 0; tt < 4; ++tt) {
            z1acc[mt][tt] = (f32x4){0,0,0,0};
            u1acc[mt][tt] = (f32x4){0,0,0,0};
        }
    #pragma unroll
    for (int kc = 0; kc < 2; ++kc) {
        __builtin_amdgcn_s_setprio(1);
        #pragma unroll
        for (int tt = 0; tt < 4; ++tt) {
            #pragma unroll
            for (int mt = 0; mt < 2; ++mt) {
                z1acc[mt][tt] = __builtin_amdgcn_mfma_f32_16x16x32_bf16(ash[kc][mt], B1h[kc][tt], z1acc[mt][tt], 0,0,0);
                z1acc[mt][tt] = __builtin_amdgcn_mfma_f32_16x16x32_bf16(asl[kc][mt], B1h[kc][tt], z1acc[mt][tt], 0,0,0);
                z1acc[mt][tt] = __builtin_amdgcn_mfma_f32_16x16x32_bf16(ash[kc][mt], B1l[kc][tt], z1acc[mt][tt], 0,0,0);
                u1acc[mt][tt] = __builtin_amdgcn_mfma_f32_16x16x32_bf16(adh[kc][mt], B1h[kc][tt], u1acc[mt][tt], 0,0,0);
                u1acc[mt][tt] = __builtin_amdgcn_mfma_f32_16x16x32_bf16(adl[kc][mt], B1h[kc][tt], u1acc[mt][tt], 0,0,0);
                u1acc[mt][tt] = __builtin_amdgcn_mfma_f32_16x16x32_bf16(adh[kc][mt], B1l[kc][tt], u1acc[mt][tt], 0,0,0);
            }
        }
        __builtin_amdgcn_s_setprio(0);
    }

    // D layout: sample row = mt*16 + lg*4 + r, col h = hh[tt]
    // publish y1 = (z1+b1)^2 and p = 2*z1*u1 as single-bf16 planes
    #pragma unroll
    for (int tt = 0; tt < 4; ++tt) {
        const int grp = hh[tt] >> 3;
        const int jb  = grp * PITCH + (hh[tt] & 7);
        #pragma unroll
        for (int mt = 0; mt < 2; ++mt) {
            #pragma unroll
            for (int r = 0; r < 4; ++r) {
                const float z  = z1acc[mt][tt][r] + bb1[tt];
                const float pv = 2.f * z * u1acc[mt][tt][r];
                const int ii = swz(grp, mt * 16 + lg * 4 + r);
                yH[jb + ii * 8] = f2bf(z * z);
                pH[jb + ii * 8] = f2bf(pv);
            }
        }
    }
    __syncthreads();                                 // (2) y/p planes visible

    // ---------- merged phase 2: z2 = y1@W2h^T  AND  q = p@W2h^T ------------
    // FULL unroll: lets the compiler software-pipeline B2h (L2) and A (LDS)
    // loads several packs ahead via register renaming.
    f32x4 z2acc[2][4], qacc[2][4];
    #pragma unroll
    for (int mt = 0; mt < 2; ++mt)
        #pragma unroll
        for (int tt = 0; tt < 4; ++tt) {
            z2acc[mt][tt] = (f32x4){0,0,0,0};
            qacc[mt][tt]  = (f32x4){0,0,0,0};
        }
    #pragma unroll
    for (int kc = 0; kc < 8; ++kc) {
        const int g = kc * 4 + lg;
        bf16x8 bh[4];
        #pragma unroll
        for (int tt = 0; tt < 4; ++tt) bh[tt] = nbh[tt];
        if (kc < 7) {                                // prefetch next-kc B2h
            const int gn = (kc + 1) * 4 + lg;
            #pragma unroll
            for (int tt = 0; tt < 4; ++tt)
                nbh[tt] = *reinterpret_cast<const bf16x8*>(ws + 32768 + (gn * 256 + hh[tt]) * 8);
        }
        bf16x8 ayh[2], aph[2];
        #pragma unroll
        for (int mt = 0; mt < 2; ++mt) {
            const int off = g * PITCH + swz(g, mt * 16 + lc) * 8;
            ayh[mt] = *reinterpret_cast<const bf16x8*>(&yH[off]);
            aph[mt] = *reinterpret_cast<const bf16x8*>(&pH[off]);
        }
        __builtin_amdgcn_s_setprio(1);
        #pragma unroll
        for (int tt = 0; tt < 4; ++tt) {
            #pragma unroll
            for (int mt = 0; mt < 2; ++mt) {
                z2acc[mt][tt] = __builtin_amdgcn_mfma_f32_16x16x32_bf16(ayh[mt], bh[tt], z2acc[mt][tt], 0,0,0);
                qacc[mt][tt]  = __builtin_amdgcn_mfma_f32_16x16x32_bf16(aph[mt], bh[tt], qacc[mt][tt], 0,0,0);
            }
        }
        __builtin_amdgcn_s_setprio(0);
    }

    // ---------- epilogue: nn = sum w3*(z2+b2)^2 ; gd = sum 2*w3*(z2+b2)*q --
    float nnp[2][4], gdp[2][4];
    #pragma unroll
    for (int mt = 0; mt < 2; ++mt)
        #pragma unroll
        for (int r = 0; r < 4; ++r) { nnp[mt][r] = 0.f; gdp[mt][r] = 0.f; }
    #pragma unroll
    for (int tt = 0; tt < 4; ++tt) {
        #pragma unroll
        for (int mt = 0; mt < 2; ++mt) {
            #pragma unroll
            for (int r = 0; r < 4; ++r) {
                const float z = z2acc[mt][tt][r] + bb2[tt];
                nnp[mt][r] += w3v[tt] * z * z;
                gdp[mt][r] += 2.f * w3v[tt] * z * qacc[mt][tt][r];
            }
        }
    }
    #pragma unroll
    for (int mt = 0; mt < 2; ++mt)
        #pragma unroll
        for (int r = 0; r < 4; ++r) {
            float a = nnp[mt][r], b = gdp[mt][r];
            #pragma unroll
            for (int o = 1; o < 16; o <<= 1) { a += __shfl_xor(a, o); b += __shfl_xor(b, o); }
            if (lc == 0) {
                red[0][wid][mt * 16 + lg * 4 + r] = a;
                red[1][wid][mt * 16 + lg * 4 + r] = b;
            }
        }
    __syncthreads();                                 // (3) red visible

    // ---------- finalize ----------
    if (t < SB) {
        const int i = t;
        float nn = 0.f, gd = 0.f;
        #pragma unroll
        for (int w = 0; w < 4; ++w) { nn += red[0][w][i]; gd += red[1][w][i]; }
        const float c  = csd[i][0];
        const float sd = csd[i][1];
        const int n = s0 + i;
        out[n]         = nn * c;                 // V
        out[N + n]     = 2.f * nn * sd + c * gd; // Vdot
        out[2 * N + n] = c;                      // circle
    }
}

extern "C" void kernel_launch(void* const* d_in, const int* in_sizes, int n_in,
                              void* d_out, int out_size, void* d_ws, size_t ws_size,
                              hipStream_t stream) {
    const float* S    = (const float*)d_in[0];
    const float* Sdot = (const float*)d_in[1];
    const float* W1   = (const float*)d_in[2];
    const float* b1   = (const float*)d_in[3];
    const float* W2   = (const float*)d_in[4];
    const float* b2   = (const float*)d_in[5];
    const float* W3   = (const float*)d_in[6];
    float* out = (float*)d_out;
    ushort* ws = (ushort*)d_ws;    // 192 KB weight planes

    prep_weights<<<40, 256, 0, stream>>>(W1, W2, ws);
    fused_mfma<<<N / SB, 256, 0, stream>>>(S, Sdot, b1, b2, W3, ws, out);
}